// Round 11
// baseline (143.261 us; speedup 1.0000x reference)
//
#include <hip/hip_runtime.h>
#include <hip/hip_bf16.h>

// QuantizedConv2d: B=8, Cin=Cout=320, H=W=64, K=3, stride=1, pad=1.
// out = scale[co] * conv_zp_padded_int8(x_int, W) + bias_eff[co]
// bias_eff[co] = bias[co] - scale[co]*zp*sum(W[co]); x padded with zp byte.

typedef int v4i __attribute__((ext_vector_type(4)));

typedef const unsigned int __attribute__((address_space(1)))* gas_uptr;
typedef unsigned int __attribute__((address_space(3)))* las_uptr;

#define B_   8
#define CIN  320
#define COUT 320
#define H_   64
#define W_   64
#define HW_  4096
#define HP   66
#define WP   66
#define XPAD_BYTES (B_*HP*WP*CIN)
#define W8_BYTES (COUT*9*CIN)

// ---------------------------------------------------------------------------
// Kernel 1: weight repack int32 [O][I][3][3] -> FRAGMENT-LINEAR int8 layout
//   w8[coT(20)][tap(9)][chunk(5)][lane(64)][16B],  lane = q*16 + colc.
// One B-fragment wave-load = one contiguous aligned 1KiB burst. (unchanged)
__global__ __launch_bounds__(256) void repack_bias_kernel(const int* __restrict__ wint,
                                                          unsigned char* __restrict__ w8,
                                                          const float* __restrict__ wsum,
                                                          const float* __restrict__ scale,
                                                          const float* __restrict__ bias,
                                                          const float* __restrict__ zp_p,
                                                          float* __restrict__ be) {
    int j = blockIdx.x * 256 + threadIdx.x;     // < 230,400 dwords
    if (j < COUT) {
        float s = 0.f;
        #pragma unroll
        for (int tp = 0; tp < 9; ++tp) s += wsum[j*9 + tp];
        be[j] = bias[j] - scale[j] * zp_p[0] * s;
    }
    int co  = j / 720;
    int r   = j - co * 720;                     // tap*80 + d
    int tap = r / 80;
    int d   = r - tap * 80;
    int ci  = d * 4;
    const int* base = wint + (co * CIN + ci) * 9 + tap;
    unsigned b0 = (unsigned)(base[0]  & 0xFF);
    unsigned b1 = (unsigned)(base[9]  & 0xFF);
    unsigned b2 = (unsigned)(base[18] & 0xFF);
    unsigned b3 = (unsigned)(base[27] & 0xFF);
    unsigned dword = b0 | (b1 << 8) | (b2 << 16) | (b3 << 24);

    int coT   = co >> 4;
    int colc  = co & 15;
    int chunk = ci >> 6;
    int q     = (ci >> 4) & 3;
    int dw    = (ci >> 2) & 3;
    int lane  = q * 16 + colc;
    int idx   = (((coT * 9 + tap) * 5 + chunk) * 64 + lane) * 4 + dw;
    ((unsigned*)w8)[idx] = dword;
}

// ---------------------------------------------------------------------------
// Kernel 2: quantize + pad (register transpose; LDS dword writes stride 81).
// (unchanged)
__global__ __launch_bounds__(256) void quant_pad_kernel(const float* __restrict__ x,
                                                        unsigned char* __restrict__ xpad,
                                                        const float* __restrict__ inv_p,
                                                        const float* __restrict__ zp_p) {
    __shared__ __align__(16) unsigned lds[64 * 81];
    int bid = blockIdx.x;
    int b  = bid / HP;
    int ph = bid - b * HP;
    int t  = threadIdx.x;
    float inv = inv_p[0];
    float zp  = zp_p[0];
    int zpi = (int)rintf(zp);
    unsigned zd = ((unsigned)(zpi & 0xFF)) * 0x01010101u;

    unsigned* rowbase = (unsigned*)(xpad + (size_t)((b * HP + ph) * WP) * CIN);

    if (ph == 0 || ph == HP - 1) {
        for (int j = t; j < WP * CIN / 4; j += 256) rowbase[j] = zd;
        return;
    }
    int h = ph - 1;
    const float* xrow = x + (size_t)b * CIN * H_ * W_ + h * W_;
    int wq = t & 15;
    int cg = t >> 4;
    #pragma unroll
    for (int i = 0; i < 5; ++i) {
        int ci0 = i * 64 + cg * 4;
        float4 f[4];
        #pragma unroll
        for (int jj = 0; jj < 4; ++jj)
            f[jj] = *(const float4*)(xrow + (size_t)(ci0 + jj) * HW_ + wq * 4);
        #pragma unroll
        for (int k = 0; k < 4; ++k) {
            unsigned d = 0;
            #pragma unroll
            for (int jj = 0; jj < 4; ++jj) {
                float v = (&f[jj].x)[k];
                float q = rintf(v * inv) + zp;
                q = fminf(fmaxf(q, -128.0f), 127.0f);
                int qi = (int)q;
                d |= ((unsigned)(qi & 0xFF)) << (8 * jj);
            }
            lds[(wq * 4 + k) * 81 + (ci0 >> 2)] = d;
        }
    }
    __syncthreads();
    if (t < 80)            rowbase[t] = zd;
    else if (t < 160)      rowbase[65 * 80 + (t - 80)] = zd;
    for (int j = t; j < 64 * 80; j += 256) {
        int p = j / 80;
        int d = j - p * 80;
        rowbase[80 + j] = lds[p * 81 + d];
    }
}

// ---------------------------------------------------------------------------
// Kernel 3: implicit-GEMM conv -- OCCUPANCY restructure: 4 blocks/CU.
// Block tile 128(M) x 80(N), grid 256x4 = 1024 blocks; 4 waves/block, each
// wave = 32(M) x 80(N) = 2x5 of 16x16x64 i8 (acc 40 VGPR).
//
// Round-10 post-mortem: FIVE intra-wave scheduling mechanisms (prefetch
// depth, setprio, L1-dedupe geometry, counted-vmcnt barriers, SGB-pinned
// emission) all measured <=1us at 2 waves/SIMD. Conclusion: the residual
// ~9.5k cy/chunk is per-wave serial operand-fill cost (B reg-fill 45KiB/
// wave/chunk through L1 ~= 5.8k cy @64B/cy + LDS + chunk-head stalls) that
// only OTHER waves can hide -- and 2/SIMD in near-lockstep cannot.
// This round doubles TLP instead of ILP: halo 4 rows -> LDS 40,960/block
// -> exactly 4 blocks/CU (163,840), 4 waves/SIMD, with uncorrelated
// barrier phases across blocks. Pipeline deliberately SIMPLIFIED back to
// 2-bank ping-pong + plain __syncthreads (naturally drained: the last
// refill is consumed before the barrier; staging issued at tap0 has ~8
// MFMA clusters of cover). VGPR budget for 4 waves/SIMD = 128: acc 40 +
// bB 40 + aB 16 + addressing fits; launch_bounds(256,4) enforces.
#define CHUNK_SLOTS 1056           // 4 rows * 66 cols * 4 sub-chunks
#define ROUNDS 5                   // ceil(1056 / 256)
#define BUF_BYTES (ROUNDS * 256 * 16)   // 20,480 B per buffer (16,896 used)

// One chunk's compute. LAST_ must be a literal 0/1; tp is unroll-constant so
// all bank indices are compile-time (rule #20).
#define CHUNK_BODY(c_, LAST_)                                                   \
{                                                                               \
    const int c__ = (c_);                                                       \
    const unsigned char* ab = Al + (c__ & 1) * BUF_BYTES;                       \
    /* chunk head: tap0 operands (A ds_read x2, B global x5). Exposed       */  \
    /* within-wave; covered cross-wave/cross-block at 4 blocks/CU.          */  \
    _Pragma("unroll")                                                           \
    for (int mi = 0; mi < 2; ++mi)                                              \
        aB[0][mi] = *(const v4i*)(ab + rt * 4224 + aoffs[0][mi]);               \
    _Pragma("unroll")                                                           \
    for (int ni = 0; ni < 5; ++ni)                                              \
        bB[0][ni] = *(const v4i*)(bbase[ni] + c__ * 1024);                      \
    _Pragma("unroll")                                                           \
    for (int tp = 0; tp < 9; ++tp) {                                            \
        if (!LAST_ && tp == 0) {    /* stage chunk c+1 into other buffer */     \
            unsigned char* dst = Al + ((c__ + 1) & 1) * BUF_BYTES;              \
            int cio = (c__ + 1) * 64;                                           \
            _Pragma("unroll")                                                   \
            for (int r = 0; r < ROUNDS; ++r)                                    \
                __builtin_amdgcn_global_load_lds(                               \
                    (gas_uptr)(const void*)(xpad + srcoff[r] + cio),            \
                    (las_uptr)(dst + r * 4096 + t * 16), 16, 0, 0);             \
        }                                                                       \
        /* refill the other bank with tap tp+1 (RAW lead = 1 cluster;    */     \
        /* WAR target was consumed at tap tp-1)                          */     \
        if (tp < 8) {                                                           \
            int tn  = tp + 1;                                                   \
            int kh2 = tn / 3;                                                   \
            int kw2 = tn - kh2 * 3;                                             \
            _Pragma("unroll")                                                   \
            for (int ni = 0; ni < 5; ++ni)                                      \
                bB[tn & 1][ni] = *(const v4i*)(bbase[ni] + (tn * 5 + c__) * 1024);\
            _Pragma("unroll")                                                   \
            for (int mi = 0; mi < 2; ++mi)                                      \
                aB[tn & 1][mi] = *(const v4i*)(ab + (rt + kh2) * 4224 + aoffs[kw2][mi]);\
        }                                                                       \
        __builtin_amdgcn_s_setprio(1);                                          \
        _Pragma("unroll")                                                       \
        for (int mi = 0; mi < 2; ++mi)                                          \
            _Pragma("unroll")                                                   \
            for (int ni = 0; ni < 5; ++ni)                                      \
                acc[mi][ni] = __builtin_amdgcn_mfma_i32_16x16x64_i8(            \
                    aB[tp & 1][mi], bB[tp & 1][ni], acc[mi][ni], 0, 0, 0);      \
        __builtin_amdgcn_s_setprio(0);                                          \
    }                                                                           \
}

__global__ __launch_bounds__(256, 4) void conv_gemm_kernel(const unsigned char* __restrict__ xpad,
                                                           const unsigned char* __restrict__ w8,
                                                           const float* __restrict__ scale,
                                                           const float* __restrict__ be,
                                                           float* __restrict__ out) {
    __shared__ __align__(16) unsigned char Al[2 * BUF_BYTES];   // 40,960 B

    int t    = threadIdx.x;
    int lane = t & 63;
    int wave = t >> 6;
    int rt   = wave >> 1;          // image row within the 2-row tile (0..1)
    int m0   = blockIdx.x * 128;   // 2 image rows of one batch image
    int n0   = blockIdx.y * 80;
    int b0   = m0 >> 12;
    int h0   = (m0 & 4095) >> 6;   // first output row of this 2-row tile

    // --- staging source offsets: slot = r*256+t -> (R,C,ql); source sub-chunk
    //     pre-swizzled: qs = ql ^ ((C>>1)&3). Slots >= 1056 clamp to slot 0
    //     (dup fetch = L1 hit; garbage lands in dead LDS tail 16,896..20,479).
    int srcoff[ROUNDS];
    #pragma unroll
    for (int r = 0; r < ROUNDS; ++r) {
        int slot = r * 256 + t;
        if (slot >= CHUNK_SLOTS) slot = 0;
        int R   = slot / 264;                 // 66 cols * 4 sub-chunks per row
        int rem = slot - R * 264;
        int C   = rem >> 2;
        int ql  = rem & 3;
        int qs  = ql ^ ((C >> 1) & 3);
        srcoff[r] = ((b0 * HP + h0 + R) * WP + C) * CIN + qs * 16;
    }

    int colc = lane & 15;
    int q    = lane >> 4;

    // --- A fragment LDS offsets (per kw, per mi); row term (rt+kh)*4224 at
    //     use (rt 0..1, kh 0..2 -> rows 0..3). Phase-uniform swizzle: within
    //     any 16-lane quarter-wave, slot-group = 4(C&1) + q^((C>>1)&3) covers
    //     all 8 bank-groups exactly twice.
    int aoffs[3][2];
    #pragma unroll
    for (int kw = 0; kw < 3; ++kw)
        #pragma unroll
        for (int mi = 0; mi < 2; ++mi) {
            int C = (wave & 1) * 32 + mi * 16 + colc + kw;
            aoffs[kw][mi] = C * 64 + ((q ^ ((C >> 1) & 3)) * 16);
        }

    // --- B fragment base pointers: fragment-linear w8, one contiguous 1KiB
    //     per (coT, tap, chunk). IDENTICAL across the block's 4 waves (and
    //     across the CU's co-resident same-y blocks) -> L1-friendly.
    const unsigned char* bbase[5];
    int coT0 = n0 >> 4;
    #pragma unroll
    for (int ni = 0; ni < 5; ++ni)
        bbase[ni] = w8 + (size_t)(coT0 + ni) * (45 * 1024) + lane * 16;

    v4i acc[2][5];
    v4i zero = {0, 0, 0, 0};
    #pragma unroll
    for (int mi = 0; mi < 2; ++mi)
        #pragma unroll
        for (int ni = 0; ni < 5; ++ni) acc[mi][ni] = zero;

    v4i bB[2][5], aB[2][2];

    // --- prologue: stage chunk 0; __syncthreads drains it (once per block).
    #pragma unroll
    for (int r = 0; r < ROUNDS; ++r)
        __builtin_amdgcn_global_load_lds((gas_uptr)(const void*)(xpad + srcoff[r]),
                                         (las_uptr)(Al + r * 4096 + t * 16), 16, 0, 0);
    __syncthreads();

    #pragma unroll 1
    for (int c = 0; c < 4; ++c) {
        CHUNK_BODY(c, 0)
        // All B refills consumed before this point; staging (issued tap 0)
        // has had ~8 MFMA clusters of cover -> the implicit vmcnt(0) here is
        // naturally drained. Cross-block phase diversity (4 blocks/CU) covers
        // the barrier itself.
        __syncthreads();
    }
    CHUNK_BODY(4, 1)       // peeled: no staging; static guards

    // Epilogue: C/D layout col = lane&15 (co), row = q*4 + reg (pixel).
    #pragma unroll
    for (int ni = 0; ni < 5; ++ni) {
        int co = n0 + ni * 16 + colc;
        float s  = scale[co];
        float bz = be[co];
        #pragma unroll
        for (int mi = 0; mi < 2; ++mi) {
            int pix = m0 + wave * 32 + mi * 16 + q * 4;
            int bb2 = pix >> 12;
            int hw  = pix & 4095;
            v4i v = acc[mi][ni];
            float4 o;
            o.x = s * (float)v.x + bz;
            o.y = s * (float)v.y + bz;
            o.z = s * (float)v.z + bz;
            o.w = s * (float)v.w + bz;
            *(float4*)(out + (size_t)(bb2 * COUT + co) * HW_ + hw) = o;
        }
    }
}

// ---------------------------------------------------------------------------
extern "C" void kernel_launch(void* const* d_in, const int* in_sizes, int n_in,
                              void* d_out, int out_size, void* d_ws, size_t ws_size,
                              hipStream_t stream) {
    const float* x     = (const float*)d_in[0];
    const int*   wint  = (const int*)d_in[1];
    const float* wsum  = (const float*)d_in[2];
    const float* scale = (const float*)d_in[3];
    const float* inv_p = (const float*)d_in[4];
    const float* zp_p  = (const float*)d_in[5];
    const float* bias  = (const float*)d_in[6];
    float* out = (float*)d_out;

    unsigned char* xpad = (unsigned char*)d_ws;
    unsigned char* w8   = xpad + XPAD_BYTES;
    float*         be   = (float*)(w8 + W8_BYTES);

    repack_bias_kernel<<<(COUT * 720) / 256, 256, 0, stream>>>(wint, w8, wsum, scale, bias, zp_p, be);
    quant_pad_kernel<<<B_ * HP, 256, 0, stream>>>(x, xpad, inv_p, zp_p);

    dim3 grid((B_ * H_ * W_) / 128, COUT / 80);       // 256 x 4 = 1024 blocks
    conv_gemm_kernel<<<grid, 256, 0, stream>>>(xpad, w8, scale, be, out);
}